// Round 17
// baseline (265.259 us; speedup 1.0000x reference)
//
#include <hip/hip_runtime.h>

#define NT 256

constexpr int R1c = 2048;
constexpr int R2c = 2624;
constexpr float EPSc = 1e-5f;

// ws float offsets (stats)
constexpr int SLOTS1  = 0;
constexpr int SLOTS1Q = 4096;
constexpr int SLOTS2  = 8192;
constexpr int SLOTS2Q = 12288;
constexpr int SLOTS3  = 16384;
constexpr int SLOTS3Q = 18432;
constexpr int STATS_ZERO_FLOATS = 20480;

// ws byte offsets
constexpr size_t ST2_OFF   = 131072;                   // bf16 transposed s
constexpr size_t ST2_BYTES = 8ull * 1024 * 4672 * 2;   // 76,546,048
constexpr size_t ZB_OFF    = ST2_OFF + ST2_BYTES;      // z bf16 [patch][64][64]
constexpr size_t ZB_BYTES  = 8192ull * 4096 * 2;       // 67,108,864
constexpr size_t Y_OFF     = ZB_OFF + ZB_BYTES;        // 143,785,984
constexpr size_t Y_BYTES   = 8192ull * 12800;          // y bf16 frag layout [patch][4][800 uints]
constexpr size_t OI_OFF    = Y_OFF;                    // o image overlays dead y

// ---- bf16 helpers -------------------------------------------------------
__device__ __forceinline__ ushort f_to_bf16(float f) {
    union { float f; unsigned int i; } v; v.f = f;
    unsigned int r = (v.i + 0x7fffu + ((v.i >> 16) & 1u)) >> 16;
    return (ushort)r;
}
__device__ __forceinline__ float bf16_to_f(ushort u) {
    union { unsigned int i; float f; } v; v.i = ((unsigned int)u) << 16; return v.f;
}
__device__ __forceinline__ float bf16lo_to_f(unsigned int u) {
    union { unsigned int i; float f; } v; v.i = u << 16; return v.f;
}
__device__ __forceinline__ float bf16hi_to_f(unsigned int u) {
    union { unsigned int i; float f; } v; v.i = u & 0xffff0000u; return v.f;
}
__device__ __forceinline__ unsigned int pack_bf16(float lo, float hi) {
    return (unsigned int)f_to_bf16(lo) | ((unsigned int)f_to_bf16(hi) << 16);
}

typedef short bf16x8 __attribute__((ext_vector_type(8)));
typedef float f32x4  __attribute__((ext_vector_type(4)));
typedef float f32x4n __attribute__((ext_vector_type(4)));   // native vec for nt-store
union FR { uint4 u4; bf16x8 v; ushort s[8]; };

__device__ __forceinline__ f32x4 mfma16(bf16x8 a, bf16x8 b, f32x4 c) {
    return __builtin_amdgcn_mfma_f32_16x16x32_bf16(a, b, c, 0, 0, 0);
}

// per-block finalize from slots: finL[ch]=a, finL[nch+ch]=b. (barrier inside)
__device__ __forceinline__ void dev_fin(const float* __restrict__ ws, int so, int sq,
        const float* __restrict__ gamma, const float* __restrict__ beta,
        int nch, float N, float* finL, int t) {
    if (t < nch) {
        float sm = 0.f, qq = 0.f;
        for (int j = 0; j < 64; j++) { sm += ws[so + t*64 + j]; qq += ws[sq + t*64 + j]; }
        float mean = sm / N;
        float var  = qq / N - mean * mean;
        float a = rsqrtf(var + EPSc) * gamma[t];
        finL[t]       = a;
        finL[nch + t] = beta[t] - mean * a;
    }
    __syncthreads();
}

// 64-param x 32-patch transpose tile body (s fp32 -> st2 bf16).
__device__ __forceinline__ void tr_tile(int bi, int p0, int q0, int t,
        const float* __restrict__ s, ushort* __restrict__ st, float* tl) {
    const int tx = t & 31, ty = t >> 5;
    const float* sb = s + (size_t)bi * 4672 * 1024;
    #pragma unroll
    for (int r = ty; r < 64; r += 8)
        tl[r * 33 + tx] = sb[(size_t)(p0 + r) * 1024 + q0 + tx];
    __syncthreads();
    unsigned int* stu = (unsigned int*)(st + (size_t)bi * 1024 * 4672);
    #pragma unroll
    for (int rr = ty; rr < 32; rr += 8) {
        int q = q0 + rr;
        stu[((size_t)q * 4672 + p0) / 2 + tx] =
            pack_bf16(tl[(2 * tx) * 33 + rr], tl[(2 * tx + 1) * 33 + rr]);
    }
}

// ---------------------------------------------------------------------------
// Transpose w1 slice only (tiles px 0..31) + zero stats slots. Grid 8192.
__global__ __launch_bounds__(256)
void transpose_w1(const float* __restrict__ s, ushort* __restrict__ st,
                  float* __restrict__ ws) {
    __shared__ float tl[2112];
    const int blk = blockIdx.x, t = threadIdx.x;
    if (blk < 80) {
        int idx = blk * 256 + t;
        if (idx < STATS_ZERO_FLOATS) ws[idx] = 0.f;
    }
    const int bi = blk >> 10, rem = blk & 1023;
    const int qy = rem >> 5, px = rem & 31;
    tr_tile(bi, px * 64, qy * 32, t, s, st, tl);
}

// ---------------------------------------------------------------------------
// K1: blocks [0,4096): 2 patches, 2 waves/patch, stage-1 MFMA + stats1 +
//     y stored DIRECTLY in fragment layout. blocks [4096,6400): w2 transpose.
__global__ __launch_bounds__(NT, 6)
void k1_w(const float* __restrict__ x, const float* __restrict__ s,
          ushort* __restrict__ st2, ushort* __restrict__ ybuf,
          float* __restrict__ ws) {
    __shared__ __align__(16) ushort frB[2 * 3584];
    __shared__ float st1[128];
    const int t = threadIdx.x, unit = blockIdx.x;

    if (unit >= 4096) {   // overlapped w2 transpose
        int u = unit - 4096;
        int bi = u / 288, rem = u - bi * 288;
        int qy = rem / 9, px = 32 + (rem - qy * 9);
        tr_tile(bi, px * 64, qy * 32, t, s, st2, (float*)frB);
        return;
    }

    const int bi = unit >> 9, f = (unit >> 4) & 31, jb = unit & 15;
    const int g0 = jb * 2, slot = unit & 63;
    const int w = t >> 6, l = t & 63, l15 = l & 15, grp = l >> 4;
    const int pl_ = w >> 1, mh = w & 1;
    const int patch = bi * 1024 + f * 32 + g0 + pl_;

    if (t < 128) {
        st1[t] = 0.f;
        int p = t >> 6, e = t & 63;
        if ((e & 15) >= 4)
            ((uint4*)frB)[p * 448 + 384 + e] = make_uint4(0u, 0u, 0u, 0u);
    }
    const ushort* wp = st2 + (size_t)patch * 4672;
    FR aw[2];
    #pragma unroll
    for (int i = 0; i < 2; i++)
        aw[i].u4 = ((const uint4*)wp)[((mh * 2 + i) * 16 + l15) * 4 + grp];

    const float* xb = x + (size_t)bi * 32 * 65536;
    for (int i = t; i < 1920; i += NT) {
        int c = i / 60, rem = i - c * 60;
        int r = rem / 6, seg = rem - r * 6;
        int row = f * 8 - 1 + r; row = row < 0 ? -row : (row > 255 ? 510 - row : row);
        int col0 = g0 * 8 - 4 + seg * 4;
        float v4[4];
        if (col0 >= 0 && col0 <= 252) {
            float4 vv = *(const float4*)(xb + (size_t)c * 65536 + row * 256 + col0);
            v4[0] = vv.x; v4[1] = vv.y; v4[2] = vv.z; v4[3] = vv.w;
        } else {
            #pragma unroll
            for (int d = 0; d < 4; d++) {
                int cc = col0 + d; cc = cc < 0 ? -cc : (cc > 255 ? 510 - cc : cc);
                v4[d] = xb[(size_t)c * 65536 + row * 256 + cc];
            }
        }
        int grpc = c >> 3, j = c & 7;
        #pragma unroll
        for (int d = 0; d < 4; d++) {
            int u = col0 + d - g0 * 8;
            ushort hv = f_to_bf16(v4[d]);
            #pragma unroll
            for (int p = 0; p < 2; p++) {
                int pc = u - 8 * p + 1;
                if (pc >= 0 && pc <= 9) {
                    int px = r * 10 + pc;
                    frB[p * 3584 + ((px >> 4) * 64 + grpc * 16 + (px & 15)) * 8 + j] = hv;
                }
            }
        }
    }
    __syncthreads();

    FR b[7];
    const uint4* bp = (const uint4*)(frB + pl_ * 3584);
    #pragma unroll
    for (int n = 0; n < 7; n++) b[n].u4 = bp[n * 64 + l];

    unsigned int* ybp = (unsigned int*)ybuf + (size_t)patch * 3200;
    float s4[8], q4[8];
    #pragma unroll
    for (int i = 0; i < 8; i++) { s4[i] = 0.f; q4[i] = 0.f; }
    #pragma unroll
    for (int i = 0; i < 2; i++) {
        int mm = mh * 2 + i;
        #pragma unroll
        for (int n = 0; n < 7; n++) {
            f32x4 z = {0.f, 0.f, 0.f, 0.f};
            f32x4 c = mfma16(aw[i].v, b[n].v, z);
            #pragma unroll
            for (int r = 0; r < 4; r++) {
                float v = c[r]; s4[i*4+r] += v; q4[i*4+r] += v * v;
            }
            uint2 pk;
            pk.x = pack_bf16(c[0], c[1]);
            pk.y = pack_bf16(c[2], c[3]);
            if (n < 6) {
                *(uint2*)(ybp + mm * 800 + n * 128 + l * 2) = pk;
            } else if (l15 < 4) {
                *(uint2*)(ybp + mm * 800 + 768 + (grp * 4 + l15) * 2) = pk;
            }
        }
    }
    #pragma unroll
    for (int i = 0; i < 8; i++) {
        float sm = s4[i], qq = q4[i];
        #pragma unroll
        for (int msk = 1; msk <= 8; msk <<= 1) { sm += __shfl_xor(sm, msk); qq += __shfl_xor(qq, msk); }
        if (l15 == 0) {
            int ch = (mh * 2 + (i >> 2)) * 16 + grp * 4 + (i & 3);
            atomicAdd(&st1[ch], sm);
            atomicAdd(&st1[64 + ch], qq);
        }
    }
    __syncthreads();
    if (t < 64) {
        atomicAdd(&ws[SLOTS1  + t * 64 + slot], st1[t]);
        atomicAdd(&ws[SLOTS1Q + t * 64 + slot], st1[64 + t]);
    }
}

// ---------------------------------------------------------------------------
// K2: blocks [0,4096): y-frag PRELOAD -> BN1 finalize (latency hidden) ->
//     BN1+relu6 -> depthwise -> stats2 -> z. blocks [4096,12288): w3 transpose.
__global__ __launch_bounds__(NT, 4)
void k2_w(const ushort* __restrict__ ybuf, const float* __restrict__ s,
          ushort* __restrict__ st2, ushort* __restrict__ zbuf,
          float* __restrict__ ws,
          const float* __restrict__ g1, const float* __restrict__ b1) {
    __shared__ __align__(16) ushort slc[4 * 1696];
    __shared__ unsigned int w2L[2 * 288];
    __shared__ float finL[128];
    __shared__ float accL[128];
    const int t = threadIdx.x, unit = blockIdx.x;

    if (unit >= 4096) {   // overlapped w3 transpose
        int u = unit - 4096;
        int bi = u >> 10, rem = u & 1023;
        int qy = rem >> 5, px = 41 + (rem & 31);
        tr_tile(bi, px * 64, qy * 32, t, s, st2, (float*)slc);
        return;
    }

    const int bi = unit >> 9, f = (unit >> 4) & 31, jb = unit & 15;
    const int g0 = jb * 2, slot = unit & 63;
    const int w = t >> 6, l = t & 63, l15 = l & 15, grp = l >> 4;
    const int pl_ = w >> 1, mh = w & 1;
    const int ch_l = l >> 2, quad = l & 3, p0 = quad * 2;
    const int patch = bi * 1024 + f * 32 + g0 + pl_;

    // --- issue bulk loads FIRST (independent of finL) ---
    const unsigned int* ybp = (const unsigned int*)ybuf + (size_t)patch * 3200;
    uint2 yv2[2][7];
    #pragma unroll
    for (int i = 0; i < 2; i++) {
        int mm = mh * 2 + i;
        #pragma unroll
        for (int n = 0; n < 7; n++) {
            if (n < 6)
                yv2[i][n] = *(const uint2*)(ybp + mm * 800 + n * 128 + l * 2);
            else if (l15 < 4)
                yv2[i][n] = *(const uint2*)(ybp + mm * 800 + 768 + (grp * 4 + l15) * 2);
            else
                yv2[i][n] = make_uint2(0u, 0u);
        }
    }
    for (int k = t; k < 576; k += NT) {
        int p = (k >= 288) ? 1 : 0;
        int kk = k - p * 288;
        const unsigned int* src = (const unsigned int*)(st2 + (size_t)(bi*1024 + f*32 + g0 + p) * 4672 + R1c);
        w2L[k] = src[kk];
    }
    if (t < 128) accL[t] = 0.f;
    // --- slot reduction overlaps the in-flight loads above; barrier inside ---
    dev_fin(ws, SLOTS1, SLOTS1Q, g1, b1, 64, 819200.0f, finL, t);

    ushort* slice = slc + w * 1696;     // [16 ch][106] ushorts
    unsigned int* sliceU = (unsigned int*)slice;
    const ushort* w2u = (const ushort*)(w2L + pl_ * 288);
    ushort* zp0 = zbuf + (size_t)patch * 4096;

    #pragma unroll
    for (int i = 0; i < 2; i++) {
        int mm = mh * 2 + i;
        int chb = grp * 4;          // local channel base within 16-ch tile
        float a0 = finL[mm*16 + chb],     bb0 = finL[64 + mm*16 + chb];
        float a1 = finL[mm*16 + chb + 1], bb1 = finL[64 + mm*16 + chb + 1];
        float a2 = finL[mm*16 + chb + 2], bb2 = finL[64 + mm*16 + chb + 2];
        float a3 = finL[mm*16 + chb + 3], bb3 = finL[64 + mm*16 + chb + 3];
        #pragma unroll
        for (int n = 0; n < 7; n++) {
            if (n < 6 || l15 < 4) {
                uint2 v = yv2[i][n];
                int px = (n < 6) ? (n * 16 + l15) : (96 + l15);
                float e0 = fminf(fmaxf(bf16lo_to_f(v.x) * a0 + bb0, 0.f), 6.f);
                float e1 = fminf(fmaxf(bf16hi_to_f(v.x) * a1 + bb1, 0.f), 6.f);
                float e2 = fminf(fmaxf(bf16lo_to_f(v.y) * a2 + bb2, 0.f), 6.f);
                float e3 = fminf(fmaxf(bf16hi_to_f(v.y) * a3 + bb3, 0.f), 6.f);
                slice[(chb + 0) * 106 + px] = f_to_bf16(e0);
                slice[(chb + 1) * 106 + px] = f_to_bf16(e1);
                slice[(chb + 2) * 106 + px] = f_to_bf16(e2);
                slice[(chb + 3) * 106 + px] = f_to_bf16(e3);
            }
        }
        // depthwise 3x3 (wave-local slice)
        float yv[4][10];
        #pragma unroll
        for (int rr = 0; rr < 4; rr++) {
            int base = ch_l * 53 + (p0 + rr) * 5;
            #pragma unroll
            for (int k = 0; k < 5; k++) {
                unsigned int u = sliceU[base + k];
                yv[rr][2*k] = bf16lo_to_f(u); yv[rr][2*k+1] = bf16hi_to_f(u);
            }
        }
        float wt[9];
        #pragma unroll
        for (int k = 0; k < 9; k++) wt[k] = bf16_to_f(w2u[(mm * 16 + ch_l) * 9 + k]);
        float za[2][8];
        #pragma unroll
        for (int rr = 0; rr < 2; rr++)
            #pragma unroll
            for (int q = 0; q < 8; q++) za[rr][q] = 0.f;
        #pragma unroll
        for (int u = 0; u < 3; u++)
            #pragma unroll
            for (int v = 0; v < 3; v++) {
                float wv = wt[u * 3 + v];
                #pragma unroll
                for (int rr = 0; rr < 2; rr++)
                    #pragma unroll
                    for (int q = 0; q < 8; q++)
                        za[rr][q] += wv * yv[rr + u][q + v];
            }
        float zs = 0.f, zq = 0.f;
        #pragma unroll
        for (int rr = 0; rr < 2; rr++)
            #pragma unroll
            for (int q = 0; q < 8; q++) { float v = za[rr][q]; zs += v; zq += v * v; }
        zs += __shfl_xor(zs, 1); zs += __shfl_xor(zs, 2);
        zq += __shfl_xor(zq, 1); zq += __shfl_xor(zq, 2);
        if (quad == 0) {
            atomicAdd(&accL[mm * 16 + ch_l], zs);
            atomicAdd(&accL[64 + mm * 16 + ch_l], zq);
        }
        ushort* zp = zp0 + (mm * 16 + ch_l) * 64 + p0 * 8;
        uint4 pk0, pk1;
        pk0.x = pack_bf16(za[0][0], za[0][1]); pk0.y = pack_bf16(za[0][2], za[0][3]);
        pk0.z = pack_bf16(za[0][4], za[0][5]); pk0.w = pack_bf16(za[0][6], za[0][7]);
        pk1.x = pack_bf16(za[1][0], za[1][1]); pk1.y = pack_bf16(za[1][2], za[1][3]);
        pk1.z = pack_bf16(za[1][4], za[1][5]); pk1.w = pack_bf16(za[1][6], za[1][7]);
        *(uint4*)zp = pk0;
        *(uint4*)(zp + 8) = pk1;
    }
    __syncthreads();
    if (t < 64) {
        atomicAdd(&ws[SLOTS2  + t * 64 + slot], accL[t]);
        atomicAdd(&ws[SLOTS2Q + t * 64 + slot], accL[64 + t]);
    }
}

// ---------------------------------------------------------------------------
// K3: w3/z PRELOAD -> BN2 finalize (hidden) -> z->LDS -> MFMA -> stats3 + o.
__global__ __launch_bounds__(NT, 4)
void k3_w(const ushort* __restrict__ zbuf, const ushort* __restrict__ st2,
          ushort* __restrict__ oi, float* __restrict__ ws,
          const float* __restrict__ g2, const float* __restrict__ b2) {
    __shared__ __align__(16) ushort zL[2 * 4224];
    __shared__ float finL[128];
    __shared__ float accL[64];
    const int t = threadIdx.x, unit = blockIdx.x;
    const int bi = unit >> 9, f = (unit >> 4) & 31, jb = unit & 15;
    const int g0 = jb * 2, slot = unit & 63;
    const int w = t >> 6, l = t & 63, l15 = l & 15, grp = l >> 4;
    const int pl_ = w >> 1, mh = w & 1;
    const int patch = bi * 1024 + f * 32 + g0 + pl_;

    // --- issue bulk loads FIRST ---
    const ushort* wp = st2 + (size_t)patch * 4672;
    FR aw[2];
    #pragma unroll
    for (int ks = 0; ks < 2; ks++)
        aw[ks].u4 = ((const uint4*)(wp + R2c))[(mh * 16 + l15) * 8 + ks * 4 + grp];
    const uint4* zsrc = (const uint4*)(zbuf + (size_t)patch * 4096);
    uint4 zr[4];
    #pragma unroll
    for (int it = 0; it < 4; it++) zr[it] = zsrc[mh * 256 + it * 64 + l];
    if (t < 64) accL[t] = 0.f;
    // --- slot reduction overlaps in-flight loads; barrier inside ---
    dev_fin(ws, SLOTS2, SLOTS2Q, g2, b2, 64, 524288.0f, finL, t);

    unsigned int* zd = (unsigned int*)zL;
    #pragma unroll
    for (int it = 0; it < 4; it++) {
        int i = mh * 256 + it * 64 + l;
        uint4 v = zr[it];
        int ch = i >> 3, px0 = (i & 7) * 8;
        float a2 = finL[ch], bb2 = finL[64 + ch];
        unsigned int uu[4] = {v.x, v.y, v.z, v.w};
        int base = pl_ * 2112 + (ch * 66 + px0) / 2;
        #pragma unroll
        for (int k = 0; k < 4; k++) {
            float lo = fminf(fmaxf(bf16lo_to_f(uu[k]) * a2 + bb2, 0.f), 6.f);
            float hi = fminf(fmaxf(bf16hi_to_f(uu[k]) * a2 + bb2, 0.f), 6.f);
            zd[base + k] = pack_bf16(lo, hi);
        }
    }
    __syncthreads();

    FR bfr[2][4];
    #pragma unroll
    for (int ks = 0; ks < 2; ks++)
        #pragma unroll
        for (int n = 0; n < 4; n++)
            #pragma unroll
            for (int j = 0; j < 8; j++)
                bfr[ks][n].s[j] = zL[pl_ * 4224 + (ks * 32 + grp * 8 + j) * 66 + n * 16 + l15];

    float s4[4], q4[4];
    #pragma unroll
    for (int r = 0; r < 4; r++) { s4[r] = 0.f; q4[r] = 0.f; }
    #pragma unroll
    for (int n = 0; n < 4; n++) {
        f32x4 z = {0.f, 0.f, 0.f, 0.f};
        f32x4 c = mfma16(aw[0].v, bfr[0][n].v, z);
        c = mfma16(aw[1].v, bfr[1][n].v, c);
        #pragma unroll
        for (int r = 0; r < 4; r++) {
            float v = c[r];
            s4[r] += v; q4[r] += v * v;
            int oc = mh * 16 + grp * 4 + r;
            int px = n * 16 + l15, p = px >> 3, q = px & 7;
            oi[((size_t)(bi * 32 + oc) * 256 + f * 8 + p) * 256 + (g0 + pl_) * 8 + q] = f_to_bf16(v);
        }
    }
    #pragma unroll
    for (int r = 0; r < 4; r++) {
        float sm = s4[r], qq = q4[r];
        #pragma unroll
        for (int msk = 1; msk <= 8; msk <<= 1) { sm += __shfl_xor(sm, msk); qq += __shfl_xor(qq, msk); }
        if (l15 == 0) {
            int oc = mh * 16 + grp * 4 + r;
            atomicAdd(&accL[oc], sm);
            atomicAdd(&accL[32 + oc], qq);
        }
    }
    __syncthreads();
    if (t < 32) {
        atomicAdd(&ws[SLOTS3  + t * 64 + slot], accL[t]);
        atomicAdd(&ws[SLOTS3Q + t * 64 + slot], accL[32 + t]);
    }
}

// ---------------------------------------------------------------------------
// K4: prefetch-pipelined; BN3 finalize hidden under first loads.
__global__ __launch_bounds__(NT, 8)
void k4_w(const float* __restrict__ x, float* __restrict__ ws,
          const ushort* __restrict__ oi, float* __restrict__ out,
          const float* __restrict__ g3, const float* __restrict__ b3) {
    __shared__ float finL[64];
    const int t = threadIdx.x;
    size_t e = ((size_t)(0 * 2048 + blockIdx.x) * 256 + t) * 4;
    uint2 ovn = *(const uint2*)(oi + e);
    float4 xvn = *(const float4*)(x + e);
    dev_fin(ws, SLOTS3, SLOTS3Q, g3, b3, 32, 524288.0f, finL, t);
    #pragma unroll
    for (int it = 0; it < 8; it++) {
        uint2 ov = ovn;
        float4 xv = xvn;
        size_t ec = ((size_t)(it * 2048 + blockIdx.x) * 256 + t) * 4;
        if (it < 7) {
            size_t en = ((size_t)((it + 1) * 2048 + blockIdx.x) * 256 + t) * 4;
            ovn = *(const uint2*)(oi + en);
            xvn = *(const float4*)(x + en);
        }
        int oc = (int)((ec >> 16) & 31);
        float a3 = finL[oc], bb3 = finL[32 + oc];
        f32x4n r;
        r.x = xv.x + bf16lo_to_f(ov.x) * a3 + bb3;
        r.y = xv.y + bf16hi_to_f(ov.x) * a3 + bb3;
        r.z = xv.z + bf16lo_to_f(ov.y) * a3 + bb3;
        r.w = xv.w + bf16hi_to_f(ov.y) * a3 + bb3;
        __builtin_nontemporal_store(r, (f32x4n*)(out + ec));
    }
}

// ---------------------------------------------------------------------------
extern "C" void kernel_launch(void* const* d_in, const int* in_sizes, int n_in,
                              void* d_out, int out_size, void* d_ws, size_t ws_size,
                              hipStream_t stream) {
    const float* x  = (const float*)d_in[0];
    const float* s  = (const float*)d_in[1];
    const float* g1 = (const float*)d_in[2];
    const float* b1 = (const float*)d_in[3];
    const float* g2 = (const float*)d_in[4];
    const float* b2 = (const float*)d_in[5];
    const float* g3 = (const float*)d_in[6];
    const float* b3 = (const float*)d_in[7];
    float* out = (float*)d_out;
    float* ws  = (float*)d_ws;

    ushort* st2 = (ushort*)((char*)d_ws + ST2_OFF);
    ushort* zb  = (ushort*)((char*)d_ws + ZB_OFF);
    ushort* yb  = (ushort*)((char*)d_ws + Y_OFF);
    ushort* oi  = (ushort*)((char*)d_ws + OI_OFF);

    transpose_w1<<<8192, 256, 0, stream>>>(s, st2, ws);
    k1_w<<<6400, NT, 0, stream>>>(x, s, st2, yb, ws);
    k2_w<<<12288, NT, 0, stream>>>(yb, s, st2, zb, ws, g1, b1);
    k3_w<<<4096, NT, 0, stream>>>(zb, st2, oi, ws, g2, b2);
    k4_w<<<2048, NT, 0, stream>>>(x, ws, oi, out, g3, b3);
}

// Round 18
// 262.525 us; speedup vs baseline: 1.0104x; 1.0104x over previous
//
#include <hip/hip_runtime.h>

#define NT 256

constexpr int R1c = 2048;
constexpr int R2c = 2624;
constexpr float EPSc = 1e-5f;

// ws float offsets (stats)
constexpr int SLOTS1  = 0;
constexpr int SLOTS1Q = 4096;
constexpr int SLOTS2  = 8192;
constexpr int SLOTS2Q = 12288;
constexpr int SLOTS3  = 16384;
constexpr int SLOTS3Q = 18432;
constexpr int STATS_ZERO_FLOATS = 20480;

// ws byte offsets
constexpr size_t ST2_OFF   = 131072;                   // bf16 transposed s
constexpr size_t ST2_BYTES = 8ull * 1024 * 4672 * 2;   // 76,546,048
constexpr size_t ZB_OFF    = ST2_OFF + ST2_BYTES;      // z bf16 [patch][64][64]
constexpr size_t ZB_BYTES  = 8192ull * 4096 * 2;       // 67,108,864
constexpr size_t Y_OFF     = ZB_OFF + ZB_BYTES;        // 143,785,984
constexpr size_t Y_BYTES   = 8192ull * 12800;          // y bf16 frag layout [patch][4][800 uints]
constexpr size_t OI_OFF    = Y_OFF;                    // o image overlays dead y

// ---- bf16 helpers -------------------------------------------------------
__device__ __forceinline__ ushort f_to_bf16(float f) {
    union { float f; unsigned int i; } v; v.f = f;
    unsigned int r = (v.i + 0x7fffu + ((v.i >> 16) & 1u)) >> 16;
    return (ushort)r;
}
__device__ __forceinline__ float bf16_to_f(ushort u) {
    union { unsigned int i; float f; } v; v.i = ((unsigned int)u) << 16; return v.f;
}
__device__ __forceinline__ float bf16lo_to_f(unsigned int u) {
    union { unsigned int i; float f; } v; v.i = u << 16; return v.f;
}
__device__ __forceinline__ float bf16hi_to_f(unsigned int u) {
    union { unsigned int i; float f; } v; v.i = u & 0xffff0000u; return v.f;
}
__device__ __forceinline__ unsigned int pack_bf16(float lo, float hi) {
    return (unsigned int)f_to_bf16(lo) | ((unsigned int)f_to_bf16(hi) << 16);
}

typedef short bf16x8 __attribute__((ext_vector_type(8)));
typedef float f32x4  __attribute__((ext_vector_type(4)));
typedef float f32x4n __attribute__((ext_vector_type(4)));
typedef unsigned int u32x2 __attribute__((ext_vector_type(2)));
typedef unsigned int u32x4 __attribute__((ext_vector_type(4)));
union FR { uint4 u4; bf16x8 v; ushort s[8]; };

__device__ __forceinline__ f32x4 mfma16(bf16x8 a, bf16x8 b, f32x4 c) {
    return __builtin_amdgcn_mfma_f32_16x16x32_bf16(a, b, c, 0, 0, 0);
}

// per-block finalize from slots: finL[ch]=a, finL[nch+ch]=b. (barrier inside)
__device__ __forceinline__ void dev_fin(const float* __restrict__ ws, int so, int sq,
        const float* __restrict__ gamma, const float* __restrict__ beta,
        int nch, float N, float* finL, int t) {
    if (t < nch) {
        float sm = 0.f, qq = 0.f;
        for (int j = 0; j < 64; j++) { sm += ws[so + t*64 + j]; qq += ws[sq + t*64 + j]; }
        float mean = sm / N;
        float var  = qq / N - mean * mean;
        float a = rsqrtf(var + EPSc) * gamma[t];
        finL[t]       = a;
        finL[nch + t] = beta[t] - mean * a;
    }
    __syncthreads();
}

// 64-param x 32-patch transpose tile body (s fp32 -> st2 bf16).
__device__ __forceinline__ void tr_tile(int bi, int p0, int q0, int t,
        const float* __restrict__ s, ushort* __restrict__ st, float* tl) {
    const int tx = t & 31, ty = t >> 5;
    const float* sb = s + (size_t)bi * 4672 * 1024;
    #pragma unroll
    for (int r = ty; r < 64; r += 8)
        tl[r * 33 + tx] = sb[(size_t)(p0 + r) * 1024 + q0 + tx];
    __syncthreads();
    unsigned int* stu = (unsigned int*)(st + (size_t)bi * 1024 * 4672);
    #pragma unroll
    for (int rr = ty; rr < 32; rr += 8) {
        int q = q0 + rr;
        stu[((size_t)q * 4672 + p0) / 2 + tx] =
            pack_bf16(tl[(2 * tx) * 33 + rr], tl[(2 * tx + 1) * 33 + rr]);
    }
}

// ---------------------------------------------------------------------------
// Transpose w1 slice only (tiles px 0..31) + zero stats slots. Grid 8192.
__global__ __launch_bounds__(256)
void transpose_w1(const float* __restrict__ s, ushort* __restrict__ st,
                  float* __restrict__ ws) {
    __shared__ float tl[2112];
    const int blk = blockIdx.x, t = threadIdx.x;
    if (blk < 80) {
        int idx = blk * 256 + t;
        if (idx < STATS_ZERO_FLOATS) ws[idx] = 0.f;
    }
    const int bi = blk >> 10, rem = blk & 1023;
    const int qy = rem >> 5, px = rem & 31;
    tr_tile(bi, px * 64, qy * 32, t, s, st, tl);
}

// ---------------------------------------------------------------------------
// K1: blocks [0,4096): 2 patches, 2 waves/patch, stage-1 MFMA + stats1 +
//     y stored in fragment layout (nontemporal). [4096,6400): w2 transpose.
__global__ __launch_bounds__(NT, 6)
void k1_w(const float* __restrict__ x, const float* __restrict__ s,
          ushort* __restrict__ st2, ushort* __restrict__ ybuf,
          float* __restrict__ ws) {
    __shared__ __align__(16) ushort frB[2 * 3584];
    __shared__ float st1[128];
    const int t = threadIdx.x, unit = blockIdx.x;

    if (unit >= 4096) {   // overlapped w2 transpose
        int u = unit - 4096;
        int bi = u / 288, rem = u - bi * 288;
        int qy = rem / 9, px = 32 + (rem - qy * 9);
        tr_tile(bi, px * 64, qy * 32, t, s, st2, (float*)frB);
        return;
    }

    const int bi = unit >> 9, f = (unit >> 4) & 31, jb = unit & 15;
    const int g0 = jb * 2, slot = unit & 63;
    const int w = t >> 6, l = t & 63, l15 = l & 15, grp = l >> 4;
    const int pl_ = w >> 1, mh = w & 1;
    const int patch = bi * 1024 + f * 32 + g0 + pl_;

    if (t < 128) {
        st1[t] = 0.f;
        int p = t >> 6, e = t & 63;
        if ((e & 15) >= 4)
            ((uint4*)frB)[p * 448 + 384 + e] = make_uint4(0u, 0u, 0u, 0u);
    }
    const ushort* wp = st2 + (size_t)patch * 4672;
    FR aw[2];
    #pragma unroll
    for (int i = 0; i < 2; i++)
        aw[i].u4 = ((const uint4*)wp)[((mh * 2 + i) * 16 + l15) * 4 + grp];

    const float* xb = x + (size_t)bi * 32 * 65536;
    for (int i = t; i < 1920; i += NT) {
        int c = i / 60, rem = i - c * 60;
        int r = rem / 6, seg = rem - r * 6;
        int row = f * 8 - 1 + r; row = row < 0 ? -row : (row > 255 ? 510 - row : row);
        int col0 = g0 * 8 - 4 + seg * 4;
        float v4[4];
        if (col0 >= 0 && col0 <= 252) {
            float4 vv = *(const float4*)(xb + (size_t)c * 65536 + row * 256 + col0);
            v4[0] = vv.x; v4[1] = vv.y; v4[2] = vv.z; v4[3] = vv.w;
        } else {
            #pragma unroll
            for (int d = 0; d < 4; d++) {
                int cc = col0 + d; cc = cc < 0 ? -cc : (cc > 255 ? 510 - cc : cc);
                v4[d] = xb[(size_t)c * 65536 + row * 256 + cc];
            }
        }
        int grpc = c >> 3, j = c & 7;
        #pragma unroll
        for (int d = 0; d < 4; d++) {
            int u = col0 + d - g0 * 8;
            ushort hv = f_to_bf16(v4[d]);
            #pragma unroll
            for (int p = 0; p < 2; p++) {
                int pc = u - 8 * p + 1;
                if (pc >= 0 && pc <= 9) {
                    int px = r * 10 + pc;
                    frB[p * 3584 + ((px >> 4) * 64 + grpc * 16 + (px & 15)) * 8 + j] = hv;
                }
            }
        }
    }
    __syncthreads();

    FR b[7];
    const uint4* bp = (const uint4*)(frB + pl_ * 3584);
    #pragma unroll
    for (int n = 0; n < 7; n++) b[n].u4 = bp[n * 64 + l];

    unsigned int* ybp = (unsigned int*)ybuf + (size_t)patch * 3200;
    float s4[8], q4[8];
    #pragma unroll
    for (int i = 0; i < 8; i++) { s4[i] = 0.f; q4[i] = 0.f; }
    #pragma unroll
    for (int i = 0; i < 2; i++) {
        int mm = mh * 2 + i;
        #pragma unroll
        for (int n = 0; n < 7; n++) {
            f32x4 z = {0.f, 0.f, 0.f, 0.f};
            f32x4 c = mfma16(aw[i].v, b[n].v, z);
            #pragma unroll
            for (int r = 0; r < 4; r++) {
                float v = c[r]; s4[i*4+r] += v; q4[i*4+r] += v * v;
            }
            u32x2 pk;
            pk.x = pack_bf16(c[0], c[1]);
            pk.y = pack_bf16(c[2], c[3]);
            if (n < 6) {
                __builtin_nontemporal_store(pk, (u32x2*)(ybp + mm * 800 + n * 128 + l * 2));
            } else if (l15 < 4) {
                __builtin_nontemporal_store(pk, (u32x2*)(ybp + mm * 800 + 768 + (grp * 4 + l15) * 2));
            }
        }
    }
    #pragma unroll
    for (int i = 0; i < 8; i++) {
        float sm = s4[i], qq = q4[i];
        #pragma unroll
        for (int msk = 1; msk <= 8; msk <<= 1) { sm += __shfl_xor(sm, msk); qq += __shfl_xor(qq, msk); }
        if (l15 == 0) {
            int ch = (mh * 2 + (i >> 2)) * 16 + grp * 4 + (i & 3);
            atomicAdd(&st1[ch], sm);
            atomicAdd(&st1[64 + ch], qq);
        }
    }
    __syncthreads();
    if (t < 64) {
        atomicAdd(&ws[SLOTS1  + t * 64 + slot], st1[t]);
        atomicAdd(&ws[SLOTS1Q + t * 64 + slot], st1[64 + t]);
    }
}

// ---------------------------------------------------------------------------
// K2: blocks [0,4096): y-frag nt-preload -> BN1 finalize -> depthwise ->
//     stats2 -> z (nt store). blocks [4096,12288): w3 transpose, overlapped.
__global__ __launch_bounds__(NT, 4)
void k2_w(const ushort* __restrict__ ybuf, const float* __restrict__ s,
          ushort* __restrict__ st2, ushort* __restrict__ zbuf,
          float* __restrict__ ws,
          const float* __restrict__ g1, const float* __restrict__ b1) {
    __shared__ __align__(16) ushort slc[4 * 1696];
    __shared__ unsigned int w2L[2 * 288];
    __shared__ float finL[128];
    __shared__ float accL[128];
    const int t = threadIdx.x, unit = blockIdx.x;

    if (unit >= 4096) {   // overlapped w3 transpose
        int u = unit - 4096;
        int bi = u >> 10, rem = u & 1023;
        int qy = rem >> 5, px = 41 + (rem & 31);
        tr_tile(bi, px * 64, qy * 32, t, s, st2, (float*)slc);
        return;
    }

    const int bi = unit >> 9, f = (unit >> 4) & 31, jb = unit & 15;
    const int g0 = jb * 2, slot = unit & 63;
    const int w = t >> 6, l = t & 63, l15 = l & 15, grp = l >> 4;
    const int pl_ = w >> 1, mh = w & 1;
    const int ch_l = l >> 2, quad = l & 3, p0 = quad * 2;
    const int patch = bi * 1024 + f * 32 + g0 + pl_;

    // --- issue bulk loads FIRST (independent of finL) ---
    const unsigned int* ybp = (const unsigned int*)ybuf + (size_t)patch * 3200;
    u32x2 yv2[2][7];
    #pragma unroll
    for (int i = 0; i < 2; i++) {
        int mm = mh * 2 + i;
        #pragma unroll
        for (int n = 0; n < 7; n++) {
            if (n < 6)
                yv2[i][n] = __builtin_nontemporal_load((const u32x2*)(ybp + mm * 800 + n * 128 + l * 2));
            else if (l15 < 4)
                yv2[i][n] = __builtin_nontemporal_load((const u32x2*)(ybp + mm * 800 + 768 + (grp * 4 + l15) * 2));
            else
                yv2[i][n] = (u32x2){0u, 0u};
        }
    }
    for (int k = t; k < 576; k += NT) {
        int p = (k >= 288) ? 1 : 0;
        int kk = k - p * 288;
        const unsigned int* src = (const unsigned int*)(st2 + (size_t)(bi*1024 + f*32 + g0 + p) * 4672 + R1c);
        w2L[k] = src[kk];
    }
    if (t < 128) accL[t] = 0.f;
    dev_fin(ws, SLOTS1, SLOTS1Q, g1, b1, 64, 819200.0f, finL, t);

    ushort* slice = slc + w * 1696;     // [16 ch][106] ushorts
    unsigned int* sliceU = (unsigned int*)slice;
    const ushort* w2u = (const ushort*)(w2L + pl_ * 288);
    ushort* zp0 = zbuf + (size_t)patch * 4096;

    #pragma unroll
    for (int i = 0; i < 2; i++) {
        int mm = mh * 2 + i;
        int chb = grp * 4;
        float a0 = finL[mm*16 + chb],     bb0 = finL[64 + mm*16 + chb];
        float a1 = finL[mm*16 + chb + 1], bb1 = finL[64 + mm*16 + chb + 1];
        float a2 = finL[mm*16 + chb + 2], bb2 = finL[64 + mm*16 + chb + 2];
        float a3 = finL[mm*16 + chb + 3], bb3 = finL[64 + mm*16 + chb + 3];
        #pragma unroll
        for (int n = 0; n < 7; n++) {
            if (n < 6 || l15 < 4) {
                u32x2 v = yv2[i][n];
                int px = (n < 6) ? (n * 16 + l15) : (96 + l15);
                float e0 = fminf(fmaxf(bf16lo_to_f(v.x) * a0 + bb0, 0.f), 6.f);
                float e1 = fminf(fmaxf(bf16hi_to_f(v.x) * a1 + bb1, 0.f), 6.f);
                float e2 = fminf(fmaxf(bf16lo_to_f(v.y) * a2 + bb2, 0.f), 6.f);
                float e3 = fminf(fmaxf(bf16hi_to_f(v.y) * a3 + bb3, 0.f), 6.f);
                slice[(chb + 0) * 106 + px] = f_to_bf16(e0);
                slice[(chb + 1) * 106 + px] = f_to_bf16(e1);
                slice[(chb + 2) * 106 + px] = f_to_bf16(e2);
                slice[(chb + 3) * 106 + px] = f_to_bf16(e3);
            }
        }
        // depthwise 3x3 (wave-local slice)
        float yv[4][10];
        #pragma unroll
        for (int rr = 0; rr < 4; rr++) {
            int base = ch_l * 53 + (p0 + rr) * 5;
            #pragma unroll
            for (int k = 0; k < 5; k++) {
                unsigned int u = sliceU[base + k];
                yv[rr][2*k] = bf16lo_to_f(u); yv[rr][2*k+1] = bf16hi_to_f(u);
            }
        }
        float wt[9];
        #pragma unroll
        for (int k = 0; k < 9; k++) wt[k] = bf16_to_f(w2u[(mm * 16 + ch_l) * 9 + k]);
        float za[2][8];
        #pragma unroll
        for (int rr = 0; rr < 2; rr++)
            #pragma unroll
            for (int q = 0; q < 8; q++) za[rr][q] = 0.f;
        #pragma unroll
        for (int u = 0; u < 3; u++)
            #pragma unroll
            for (int v = 0; v < 3; v++) {
                float wv = wt[u * 3 + v];
                #pragma unroll
                for (int rr = 0; rr < 2; rr++)
                    #pragma unroll
                    for (int q = 0; q < 8; q++)
                        za[rr][q] += wv * yv[rr + u][q + v];
            }
        float zs = 0.f, zq = 0.f;
        #pragma unroll
        for (int rr = 0; rr < 2; rr++)
            #pragma unroll
            for (int q = 0; q < 8; q++) { float v = za[rr][q]; zs += v; zq += v * v; }
        zs += __shfl_xor(zs, 1); zs += __shfl_xor(zs, 2);
        zq += __shfl_xor(zq, 1); zq += __shfl_xor(zq, 2);
        if (quad == 0) {
            atomicAdd(&accL[mm * 16 + ch_l], zs);
            atomicAdd(&accL[64 + mm * 16 + ch_l], zq);
        }
        ushort* zp = zp0 + (mm * 16 + ch_l) * 64 + p0 * 8;
        u32x4 pk0, pk1;
        pk0.x = pack_bf16(za[0][0], za[0][1]); pk0.y = pack_bf16(za[0][2], za[0][3]);
        pk0.z = pack_bf16(za[0][4], za[0][5]); pk0.w = pack_bf16(za[0][6], za[0][7]);
        pk1.x = pack_bf16(za[1][0], za[1][1]); pk1.y = pack_bf16(za[1][2], za[1][3]);
        pk1.z = pack_bf16(za[1][4], za[1][5]); pk1.w = pack_bf16(za[1][6], za[1][7]);
        __builtin_nontemporal_store(pk0, (u32x4*)zp);
        __builtin_nontemporal_store(pk1, (u32x4*)(zp + 8));
    }
    __syncthreads();
    if (t < 64) {
        atomicAdd(&ws[SLOTS2  + t * 64 + slot], accL[t]);
        atomicAdd(&ws[SLOTS2Q + t * 64 + slot], accL[64 + t]);
    }
}

// ---------------------------------------------------------------------------
// K3: w3/z nt-preload -> BN2 finalize (hidden) -> z->LDS -> MFMA -> stats3 + o.
__global__ __launch_bounds__(NT, 4)
void k3_w(const ushort* __restrict__ zbuf, const ushort* __restrict__ st2,
          ushort* __restrict__ oi, float* __restrict__ ws,
          const float* __restrict__ g2, const float* __restrict__ b2) {
    __shared__ __align__(16) ushort zL[2 * 4224];
    __shared__ float finL[128];
    __shared__ float accL[64];
    const int t = threadIdx.x, unit = blockIdx.x;
    const int bi = unit >> 9, f = (unit >> 4) & 31, jb = unit & 15;
    const int g0 = jb * 2, slot = unit & 63;
    const int w = t >> 6, l = t & 63, l15 = l & 15, grp = l >> 4;
    const int pl_ = w >> 1, mh = w & 1;
    const int patch = bi * 1024 + f * 32 + g0 + pl_;

    // --- issue bulk loads FIRST ---
    const ushort* wp = st2 + (size_t)patch * 4672;
    FR aw[2];
    #pragma unroll
    for (int ks = 0; ks < 2; ks++)
        aw[ks].u4 = ((const uint4*)(wp + R2c))[(mh * 16 + l15) * 8 + ks * 4 + grp];
    const u32x4* zsrc = (const u32x4*)(zbuf + (size_t)patch * 4096);
    u32x4 zr[4];
    #pragma unroll
    for (int it = 0; it < 4; it++)
        zr[it] = __builtin_nontemporal_load(zsrc + mh * 256 + it * 64 + l);
    if (t < 64) accL[t] = 0.f;
    dev_fin(ws, SLOTS2, SLOTS2Q, g2, b2, 64, 524288.0f, finL, t);

    unsigned int* zd = (unsigned int*)zL;
    #pragma unroll
    for (int it = 0; it < 4; it++) {
        int i = mh * 256 + it * 64 + l;
        u32x4 v = zr[it];
        int ch = i >> 3, px0 = (i & 7) * 8;
        float a2 = finL[ch], bb2 = finL[64 + ch];
        unsigned int uu[4] = {v.x, v.y, v.z, v.w};
        int base = pl_ * 2112 + (ch * 66 + px0) / 2;
        #pragma unroll
        for (int k = 0; k < 4; k++) {
            float lo = fminf(fmaxf(bf16lo_to_f(uu[k]) * a2 + bb2, 0.f), 6.f);
            float hi = fminf(fmaxf(bf16hi_to_f(uu[k]) * a2 + bb2, 0.f), 6.f);
            zd[base + k] = pack_bf16(lo, hi);
        }
    }
    __syncthreads();

    FR bfr[2][4];
    #pragma unroll
    for (int ks = 0; ks < 2; ks++)
        #pragma unroll
        for (int n = 0; n < 4; n++)
            #pragma unroll
            for (int j = 0; j < 8; j++)
                bfr[ks][n].s[j] = zL[pl_ * 4224 + (ks * 32 + grp * 8 + j) * 66 + n * 16 + l15];

    float s4[4], q4[4];
    #pragma unroll
    for (int r = 0; r < 4; r++) { s4[r] = 0.f; q4[r] = 0.f; }
    #pragma unroll
    for (int n = 0; n < 4; n++) {
        f32x4 z = {0.f, 0.f, 0.f, 0.f};
        f32x4 c = mfma16(aw[0].v, bfr[0][n].v, z);
        c = mfma16(aw[1].v, bfr[1][n].v, c);
        #pragma unroll
        for (int r = 0; r < 4; r++) {
            float v = c[r];
            s4[r] += v; q4[r] += v * v;
            int oc = mh * 16 + grp * 4 + r;
            int px = n * 16 + l15, p = px >> 3, q = px & 7;
            oi[((size_t)(bi * 32 + oc) * 256 + f * 8 + p) * 256 + (g0 + pl_) * 8 + q] = f_to_bf16(v);
        }
    }
    #pragma unroll
    for (int r = 0; r < 4; r++) {
        float sm = s4[r], qq = q4[r];
        #pragma unroll
        for (int msk = 1; msk <= 8; msk <<= 1) { sm += __shfl_xor(sm, msk); qq += __shfl_xor(qq, msk); }
        if (l15 == 0) {
            int oc = mh * 16 + grp * 4 + r;
            atomicAdd(&accL[oc], sm);
            atomicAdd(&accL[32 + oc], qq);
        }
    }
    __syncthreads();
    if (t < 32) {
        atomicAdd(&ws[SLOTS3  + t * 64 + slot], accL[t]);
        atomicAdd(&ws[SLOTS3Q + t * 64 + slot], accL[32 + t]);
    }
}

// ---------------------------------------------------------------------------
// K4: prefetch-pipelined, all-nontemporal stream.
__global__ __launch_bounds__(NT, 8)
void k4_w(const float* __restrict__ x, float* __restrict__ ws,
          const ushort* __restrict__ oi, float* __restrict__ out,
          const float* __restrict__ g3, const float* __restrict__ b3) {
    __shared__ float finL[64];
    const int t = threadIdx.x;
    size_t e = ((size_t)(0 * 2048 + blockIdx.x) * 256 + t) * 4;
    u32x2 ovn = __builtin_nontemporal_load((const u32x2*)(oi + e));
    f32x4n xvn = __builtin_nontemporal_load((const f32x4n*)(x + e));
    dev_fin(ws, SLOTS3, SLOTS3Q, g3, b3, 32, 524288.0f, finL, t);
    #pragma unroll
    for (int it = 0; it < 8; it++) {
        u32x2 ov = ovn;
        f32x4n xv = xvn;
        size_t ec = ((size_t)(it * 2048 + blockIdx.x) * 256 + t) * 4;
        if (it < 7) {
            size_t en = ((size_t)((it + 1) * 2048 + blockIdx.x) * 256 + t) * 4;
            ovn = __builtin_nontemporal_load((const u32x2*)(oi + en));
            xvn = __builtin_nontemporal_load((const f32x4n*)(x + en));
        }
        int oc = (int)((ec >> 16) & 31);
        float a3 = finL[oc], bb3 = finL[32 + oc];
        f32x4n r;
        r.x = xv.x + bf16lo_to_f(ov.x) * a3 + bb3;
        r.y = xv.y + bf16hi_to_f(ov.x) * a3 + bb3;
        r.z = xv.z + bf16lo_to_f(ov.y) * a3 + bb3;
        r.w = xv.w + bf16hi_to_f(ov.y) * a3 + bb3;
        __builtin_nontemporal_store(r, (f32x4n*)(out + ec));
    }
}

// ---------------------------------------------------------------------------
extern "C" void kernel_launch(void* const* d_in, const int* in_sizes, int n_in,
                              void* d_out, int out_size, void* d_ws, size_t ws_size,
                              hipStream_t stream) {
    const float* x  = (const float*)d_in[0];
    const float* s  = (const float*)d_in[1];
    const float* g1 = (const float*)d_in[2];
    const float* b1 = (const float*)d_in[3];
    const float* g2 = (const float*)d_in[4];
    const float* b2 = (const float*)d_in[5];
    const float* g3 = (const float*)d_in[6];
    const float* b3 = (const float*)d_in[7];
    float* out = (float*)d_out;
    float* ws  = (float*)d_ws;

    ushort* st2 = (ushort*)((char*)d_ws + ST2_OFF);
    ushort* zb  = (ushort*)((char*)d_ws + ZB_OFF);
    ushort* yb  = (ushort*)((char*)d_ws + Y_OFF);
    ushort* oi  = (ushort*)((char*)d_ws + OI_OFF);

    transpose_w1<<<8192, 256, 0, stream>>>(s, st2, ws);
    k1_w<<<6400, NT, 0, stream>>>(x, s, st2, yb, ws);
    k2_w<<<12288, NT, 0, stream>>>(yb, s, st2, zb, ws, g1, b1);
    k3_w<<<4096, NT, 0, stream>>>(zb, st2, oi, ws, g2, b2);
    k4_w<<<2048, NT, 0, stream>>>(x, ws, oi, out, g3, b3);
}